// Round 9
// baseline (820.105 us; speedup 1.0000x reference)
//
#include <hip/hip_runtime.h>
#include <hip/hip_bf16.h>

typedef __hip_bfloat16 bf16;
typedef __attribute__((ext_vector_type(8))) short short8;   // MFMA A/B frag (8 bf16)
typedef __attribute__((ext_vector_type(4))) float floatx4;  // MFMA C/D frag

#define NE 524288
#define NA 16384
#define E   64       // edges per chunk
#define AGB 16       // agents per block
#define S1 260       // LDS act row stride (shorts)
#define SH3 68       // h3 overlay row stride (floats), inside wave's own quarter
#define SACC 68      // acc row stride (floats): 64 feats + 2 cb + 2 pad

__device__ __forceinline__ float ld(const void* p, long i, int f32) {
    return f32 ? ((const float*)p)[i] : __bfloat162float(((const bf16*)p)[i]);
}
__device__ __forceinline__ short f2bs(float f) {
    bf16 h = __float2bfloat16(f);
    return *(short*)&h;
}
__device__ __forceinline__ float bs2f(short s) {
    union { unsigned u; float f; } c;
    c.u = ((unsigned)(unsigned short)s) << 16;
    return c.f;
}
__device__ __forceinline__ unsigned pk(float a, float b) {
    return ((unsigned)(unsigned short)f2bs(b) << 16) | (unsigned)(unsigned short)f2bs(a);
}

// ---------------------------------------------------------------------------
// rowptr: rp[a] = lower_bound(ids, a); rp[NA] = NE. ids is sorted.
// ---------------------------------------------------------------------------
__global__ void rowptr_kernel(const int* __restrict__ ids, int* __restrict__ rp) {
    const int i = blockIdx.x * blockDim.x + threadIdx.x;
    if (i > NA) return;
    if (i == NA) { rp[i] = NE; return; }
    int lo = 0, hi = NE;
    while (lo < hi) {
        const int mid = (lo + hi) >> 1;
        if (ids[mid] < i) lo = mid + 1; else hi = mid;
    }
    rp[i] = lo;
}

// ---------------------------------------------------------------------------
// Weight prep (dtype detector fused in). Coalesced transpose reads.
// ---------------------------------------------------------------------------
__global__ void prep_weights_kernel(
    const void* __restrict__ Wp1, const void* __restrict__ bp1,
    const void* __restrict__ Wp2, const void* __restrict__ bp2,
    const void* __restrict__ Wp3, const void* __restrict__ bp3,
    const void* __restrict__ Wr1, const void* __restrict__ br1,
    const void* __restrict__ Wr2, const void* __restrict__ br2,
    const void* __restrict__ Wr3, const void* __restrict__ br3,
    short* __restrict__ Wp1Tp, short* __restrict__ Wp2T, short* __restrict__ Wp3T,
    short* __restrict__ Wr1T,  short* __restrict__ Wr2T,
    float* __restrict__ bp1f, float* __restrict__ bp2f, float* __restrict__ bp3f,
    float* __restrict__ br1f, float* __restrict__ br2f,
    float* __restrict__ Wr3f, float* __restrict__ br3f,
    int* __restrict__ flag)
{
    __shared__ int sflag;
    if (threadIdx.x < 64) {
        const unsigned short* w = (const unsigned short*)Wp2;
        int bad = 0;
        for (int i = threadIdx.x; i < 1024; i += 64) {
            const int e = (w[i] >> 7) & 0xFF;
            if (e >= 131) bad = 1;                // |v|>=16 / inf / nan -> f32 bits
        }
        const unsigned long long m = __ballot(bad);
        if (threadIdx.x == 0) {
            sflag = (m != 0ull) ? 1 : 0;
            if (blockIdx.x == 0) *flag = sflag;
        }
    }
    __syncthreads();
    const int f32 = sflag;

    const int stride = gridDim.x * blockDim.x;
    for (int i = blockIdx.x * blockDim.x + threadIdx.x; i < 173634; i += stride) {
        if (i < 65536) {                       // Wp2: i = k*256+n (coalesced read)
            const int k = i >> 8, n = i & 255;
            Wp2T[n * 256 + k] = f2bs(ld(Wp2, i, f32));
        } else if (i < 81920) {                // Wp3: j = k*64+n (coalesced read)
            const int j = i - 65536, k = j >> 6, n = j & 63;
            Wp3T[n * 256 + k] = f2bs(ld(Wp3, j, f32));
        } else if (i < 90112) {                // Wp1Tp[n][k<32], zero-pad k>=4
            const int j = i - 81920, n = j >> 5, k = j & 31;
            Wp1Tp[j] = (k < 4) ? f2bs(ld(Wp1, (long)k * 256 + n, f32)) : (short)0;
        } else if (i < 106496) {               // Wr1: j = k*256+n (coalesced read)
            const int j = i - 90112, k = j >> 8, n = j & 255;
            Wr1T[n * 64 + k] = f2bs(ld(Wr1, j, f32));
        } else if (i < 172032) {               // Wr2: j = k*256+n (coalesced read)
            const int j = i - 106496, k = j >> 8, n = j & 255;
            Wr2T[n * 256 + k] = f2bs(ld(Wr2, j, f32));
        } else if (i < 172288) { bp1f[i - 172032] = ld(bp1, i - 172032, f32); }
        else if (i < 172544) { bp2f[i - 172288] = ld(bp2, i - 172288, f32); }
        else if (i < 172608) { bp3f[i - 172544] = ld(bp3, i - 172544, f32); }
        else if (i < 172864) { br1f[i - 172608] = ld(br1, i - 172608, f32); }
        else if (i < 173120) { br2f[i - 172864] = ld(br2, i - 172864, f32); }
        else if (i < 173632) { Wr3f[i - 173120] = ld(Wr3, i - 173120, f32); }
        else                 { br3f[i - 173632] = ld(br3, i - 173632, f32); }
    }
}

// ---------------------------------------------------------------------------
// FUSED kernel: block b owns agents [b*16, b*16+16) and their contiguous
// edge range [rp[a0], rp[a0+16]) (ids sorted). Edge MLP chunks of 64 edges
// accumulate h3 + barrier into a 17x68 f32 LDS accumulator (row 16 = trash
// for tail lanes, cols 64-65 = barrier), then the agent MLP runs in-block.
// No global atomics, no agg round-trip, no second kernel.
// ---------------------------------------------------------------------------
__global__ __launch_bounds__(256, 4) void fused_kernel(
    const void* __restrict__ ef, const int* __restrict__ ids,
    const int* __restrict__ rp,
    const short* __restrict__ Wp1Tp, const float* __restrict__ bp1f,
    const short* __restrict__ Wp2T, const float* __restrict__ bp2f,
    const short* __restrict__ Wp3T, const float* __restrict__ bp3f,
    const short* __restrict__ Wr1T, const float* __restrict__ br1f,
    const short* __restrict__ Wr2T, const float* __restrict__ br2f,
    const float* __restrict__ Wr3f, const float* __restrict__ br3f,
    void* __restrict__ out, const int* __restrict__ flag)
{
    __shared__ __align__(16) short hs[E * S1];        // 33.3 KB act buffer
    __shared__ __align__(16) float accf[17 * SACC];   // 4.6 KB agent accumulator
    __shared__ int sid[E];

    const int t = threadIdx.x;
    const int f32 = *flag;
    const int wave = t >> 6, lane = t & 63, quad = lane >> 4, ln = lane & 15;
    const int nb = wave * 64;
    const int a0 = blockIdx.x * AGB;
    const int rs = rp[a0], re = rp[a0 + AGB];

    for (int i = t; i < 17 * SACC; i += 256) accf[i] = 0.f;

    float* h3f = (float*)&hs[wave * 16 * S1];   // wave's own quarter (h3 overlay)
    const int nch = (re - rs + 63) >> 6;

    for (int c = 0; c < nch; ++c) {
        __syncthreads();   // covers acc-init (c=0) / prev chunk's scatter reads
        const long e0 = (long)rs + (long)c * 64;

        // ---- stage: sid + barrier contribution ----
        if (t < E) {
            const long e = e0 + t;
            int idx = 16;                       // trash row for tail lanes
            if (e < re) {
                idx = ids[e] - a0;
                const float px = ld(ef, e * 4 + 0, f32);
                const float py = ld(ef, e * 4 + 1, f32);
                const float d = sqrtf(px * px + py * py);
                const float inv = 1.0f / (d * (d - 0.18f));
                atomicAdd(&accf[idx * SACC + 64], -px * inv);
                atomicAdd(&accf[idx * SACC + 65], -py * inv);
            }
            sid[t] = idx;
        }

        // ---- layer 1: h1 = relu(x @ Wp1 + bp1); A=Wp1^T, B=x frags ----
        {
            short8 b[4];
            #pragma unroll
            for (int mt = 0; mt < 4; ++mt) {
                short8 v = {};
                const long e = e0 + mt * 16 + ln;
                if (quad == 0 && e < re) {
                    if (f32) {
                        const float4 x = ((const float4*)ef)[e];
                        v[0] = f2bs(x.x); v[1] = f2bs(x.y); v[2] = f2bs(x.z); v[3] = f2bs(x.w);
                    } else {
                        const int2 x = ((const int2*)ef)[e];
                        v[0] = (short)(x.x & 0xffff); v[1] = (short)((unsigned)x.x >> 16);
                        v[2] = (short)(x.y & 0xffff); v[3] = (short)((unsigned)x.y >> 16);
                    }
                }
                b[mt] = v;
            }
            floatx4 acc[4][4];
            #pragma unroll
            for (int nt = 0; nt < 4; ++nt) {
                const float4 bv = *(const float4*)&bp1f[nb + nt * 16 + quad * 4];
                const floatx4 bi = { bv.x, bv.y, bv.z, bv.w };
                #pragma unroll
                for (int mt = 0; mt < 4; ++mt) acc[mt][nt] = bi;
            }
            #pragma unroll
            for (int nt = 0; nt < 4; ++nt) {
                const short8 a = *(const short8*)&Wp1Tp[(nb + nt * 16 + ln) * 32 + quad * 8];
                #pragma unroll
                for (int mt = 0; mt < 4; ++mt)
                    acc[mt][nt] = __builtin_amdgcn_mfma_f32_16x16x32_bf16(a, b[mt], acc[mt][nt], 0, 0, 0);
            }
            #pragma unroll
            for (int mt = 0; mt < 4; ++mt)
                #pragma unroll
                for (int nt = 0; nt < 4; ++nt) {
                    const floatx4 v = acc[mt][nt];
                    uint2 w;
                    w.x = pk(fmaxf(v[0], 0.f), fmaxf(v[1], 0.f));
                    w.y = pk(fmaxf(v[2], 0.f), fmaxf(v[3], 0.f));
                    *(uint2*)&hs[(mt * 16 + ln) * S1 + nb + nt * 16 + quad * 4] = w;
                }
        }
        __syncthreads();

        // ---- layer 2: h2 = relu(h1 @ Wp2 + bp2); lookahead-1 prefetch ----
        short8 v3cur[4];
        {
            floatx4 acc[4][4];
            #pragma unroll
            for (int nt = 0; nt < 4; ++nt) {
                const float4 bv = *(const float4*)&bp2f[nb + nt * 16 + quad * 4];
                const floatx4 bi = { bv.x, bv.y, bv.z, bv.w };
                #pragma unroll
                for (int mt = 0; mt < 4; ++mt) acc[mt][nt] = bi;
            }
            short8 wcur[4], wnxt[4];
            #pragma unroll
            for (int nt = 0; nt < 4; ++nt)
                wcur[nt] = *(const short8*)&Wp2T[(nb + nt * 16 + ln) * 256 + quad * 8];
            #pragma unroll
            for (int ks = 0; ks < 8; ++ks) {
                if (ks < 7) {
                    #pragma unroll
                    for (int nt = 0; nt < 4; ++nt)
                        wnxt[nt] = *(const short8*)&Wp2T[(nb + nt * 16 + ln) * 256 + (ks + 1) * 32 + quad * 8];
                }
                short8 b[4];
                #pragma unroll
                for (int mt = 0; mt < 4; ++mt)
                    b[mt] = *(const short8*)&hs[(mt * 16 + ln) * S1 + ks * 32 + quad * 8];
                #pragma unroll
                for (int mt = 0; mt < 4; ++mt)
                    #pragma unroll
                    for (int nt = 0; nt < 4; ++nt)
                        acc[mt][nt] = __builtin_amdgcn_mfma_f32_16x16x32_bf16(wcur[nt], b[mt], acc[mt][nt], 0, 0, 0);
                #pragma unroll
                for (int nt = 0; nt < 4; ++nt) wcur[nt] = wnxt[nt];
            }
            // L3 ks=0 weights issued here: latency overlaps barrier + epilogue
            #pragma unroll
            for (int nt = 0; nt < 4; ++nt)
                v3cur[nt] = *(const short8*)&Wp3T[(nt * 16 + ln) * 256 + quad * 8];

            __syncthreads();   // all h1 reads complete before overwrite
            #pragma unroll
            for (int mt = 0; mt < 4; ++mt)
                #pragma unroll
                for (int nt = 0; nt < 4; ++nt) {
                    const floatx4 v = acc[mt][nt];
                    uint2 w;
                    w.x = pk(fmaxf(v[0], 0.f), fmaxf(v[1], 0.f));
                    w.y = pk(fmaxf(v[2], 0.f), fmaxf(v[3], 0.f));
                    *(uint2*)&hs[(mt * 16 + ln) * S1 + nb + nt * 16 + quad * 4] = w;
                }
        }
        __syncthreads();

        // ---- layer 3: h3 = h2 @ Wp3 + bp3; per-wave 16-edge tile ----
        {
            floatx4 acc[4];
            #pragma unroll
            for (int nt = 0; nt < 4; ++nt) {
                const float4 bv = *(const float4*)&bp3f[nt * 16 + quad * 4];
                acc[nt] = (floatx4){ bv.x, bv.y, bv.z, bv.w };
            }
            short8 v3nxt[4];
            #pragma unroll
            for (int ks = 0; ks < 8; ++ks) {
                if (ks < 7) {
                    #pragma unroll
                    for (int nt = 0; nt < 4; ++nt)
                        v3nxt[nt] = *(const short8*)&Wp3T[(nt * 16 + ln) * 256 + (ks + 1) * 32 + quad * 8];
                }
                const short8 b = *(const short8*)&hs[(wave * 16 + ln) * S1 + ks * 32 + quad * 8];
                #pragma unroll
                for (int nt = 0; nt < 4; ++nt)
                    acc[nt] = __builtin_amdgcn_mfma_f32_16x16x32_bf16(v3cur[nt], b, acc[nt], 0, 0, 0);
                #pragma unroll
                for (int nt = 0; nt < 4; ++nt) v3cur[nt] = v3nxt[nt];
            }
            #pragma unroll
            for (int nt = 0; nt < 4; ++nt) {
                float4 v = { acc[nt][0], acc[nt][1], acc[nt][2], acc[nt][3] };
                *(float4*)&h3f[ln * SH3 + nt * 16 + quad * 4] = v;
            }
        }

        // ---- scatter: run-length combine into LDS accumulator ----
        {
            const int w0 = wave * 16;
            int cur = sid[w0];
            float local = h3f[lane];
            #pragma unroll
            for (int e = 1; e < 16; ++e) {
                const int id = sid[w0 + e];
                const float v = h3f[e * SH3 + lane];
                if (id == cur) local += v;
                else { atomicAdd(&accf[cur * SACC + lane], local); cur = id; local = v; }
            }
            atomicAdd(&accf[cur * SACC + lane], local);
        }
    }
    __syncthreads();

    // ================= agent MLP on this block's 16 agents =================
    // ---- r1 = relu(accbf @ Wr1 + br1), M=16, K=64 ----
    {
        floatx4 acc[4];
        #pragma unroll
        for (int nt = 0; nt < 4; ++nt) {
            const float4 bv = *(const float4*)&br1f[nb + nt * 16 + quad * 4];
            acc[nt] = (floatx4){ bv.x, bv.y, bv.z, bv.w };
        }
        #pragma unroll
        for (int ks = 0; ks < 2; ++ks) {
            const float4 f0 = *(const float4*)&accf[ln * SACC + ks * 32 + quad * 8];
            const float4 f1 = *(const float4*)&accf[ln * SACC + ks * 32 + quad * 8 + 4];
            short8 b;
            b[0] = f2bs(f0.x); b[1] = f2bs(f0.y); b[2] = f2bs(f0.z); b[3] = f2bs(f0.w);
            b[4] = f2bs(f1.x); b[5] = f2bs(f1.y); b[6] = f2bs(f1.z); b[7] = f2bs(f1.w);
            #pragma unroll
            for (int nt = 0; nt < 4; ++nt) {
                const short8 a = *(const short8*)&Wr1T[(nb + nt * 16 + ln) * 64 + ks * 32 + quad * 8];
                acc[nt] = __builtin_amdgcn_mfma_f32_16x16x32_bf16(a, b, acc[nt], 0, 0, 0);
            }
        }
        __syncthreads();   // hs free (last h3f read done above)
        #pragma unroll
        for (int nt = 0; nt < 4; ++nt) {
            const floatx4 v = acc[nt];
            uint2 w;
            w.x = pk(fmaxf(v[0], 0.f), fmaxf(v[1], 0.f));
            w.y = pk(fmaxf(v[2], 0.f), fmaxf(v[3], 0.f));
            *(uint2*)&hs[ln * S1 + nb + nt * 16 + quad * 4] = w;
        }
    }
    __syncthreads();

    // ---- r2 = relu(r1 @ Wr2 + br2), M=16, K=256 ----
    {
        floatx4 acc[4];
        #pragma unroll
        for (int nt = 0; nt < 4; ++nt) {
            const float4 bv = *(const float4*)&br2f[nb + nt * 16 + quad * 4];
            acc[nt] = (floatx4){ bv.x, bv.y, bv.z, bv.w };
        }
        short8 wcur[4], wnxt[4];
        #pragma unroll
        for (int nt = 0; nt < 4; ++nt)
            wcur[nt] = *(const short8*)&Wr2T[(nb + nt * 16 + ln) * 256 + quad * 8];
        #pragma unroll
        for (int ks = 0; ks < 8; ++ks) {
            if (ks < 7) {
                #pragma unroll
                for (int nt = 0; nt < 4; ++nt)
                    wnxt[nt] = *(const short8*)&Wr2T[(nb + nt * 16 + ln) * 256 + (ks + 1) * 32 + quad * 8];
            }
            const short8 b = *(const short8*)&hs[ln * S1 + ks * 32 + quad * 8];
            #pragma unroll
            for (int nt = 0; nt < 4; ++nt)
                acc[nt] = __builtin_amdgcn_mfma_f32_16x16x32_bf16(wcur[nt], b, acc[nt], 0, 0, 0);
            #pragma unroll
            for (int nt = 0; nt < 4; ++nt) wcur[nt] = wnxt[nt];
        }
        __syncthreads();   // all r1 reads done
        #pragma unroll
        for (int nt = 0; nt < 4; ++nt) {
            const floatx4 v = acc[nt];
            uint2 w;
            w.x = pk(fmaxf(v[0], 0.f), fmaxf(v[1], 0.f));
            w.y = pk(fmaxf(v[2], 0.f), fmaxf(v[3], 0.f));
            *(uint2*)&hs[ln * S1 + nb + nt * 16 + quad * 4] = w;
        }
    }
    __syncthreads();

    // ---- out = r2 @ Wr3 + br3 + barrier (N=2, VALU, 16-way K-split) ----
    float* partf = (float*)&hs[16 * S1];   // rows 16+ are free
    {
        const int m = t & 15;              // agent
        const int p = t >> 4;              // 16 K-parts of 16
        const int k0 = p * 16;
        const short8 h0 = *(const short8*)&hs[m * S1 + k0];
        const short8 h1 = *(const short8*)&hs[m * S1 + k0 + 8];
        float v0 = 0.f, v1 = 0.f;
        #pragma unroll
        for (int j = 0; j < 8; ++j) {
            const float a = bs2f(h0[j]), b = bs2f(h1[j]);
            v0 = fmaf(a, Wr3f[(k0 + j) * 2 + 0], fmaf(b, Wr3f[(k0 + 8 + j) * 2 + 0], v0));
            v1 = fmaf(a, Wr3f[(k0 + j) * 2 + 1], fmaf(b, Wr3f[(k0 + 8 + j) * 2 + 1], v1));
        }
        partf[(p * 16 + m) * 2 + 0] = v0;
        partf[(p * 16 + m) * 2 + 1] = v1;
    }
    __syncthreads();
    if (t < 32) {
        const int m = t >> 1, o = t & 1;
        float s = br3f[o] + accf[m * SACC + 64 + o];
        #pragma unroll
        for (int p = 0; p < 16; ++p) s += partf[(p * 16 + m) * 2 + o];
        if (f32) ((float*)out)[(a0 + m) * 2 + o] = s;
        else     ((bf16*)out)[(a0 + m) * 2 + o] = __float2bfloat16(s);
    }
}

extern "C" void kernel_launch(void* const* d_in, const int* in_sizes, int n_in,
                              void* d_out, int out_size, void* d_ws, size_t ws_size,
                              hipStream_t stream)
{
    (void)in_sizes; (void)n_in; (void)out_size;

    const void* ef  = d_in[0];
    const int*  ids = (const int*)d_in[1];

    char* p = (char*)d_ws;
    int*   flag  = (int*)p;        p += 256;
    int*   rp    = (int*)p;        p += (NA + 1 + 63) / 64 * 64 * 4;
    short* Wp1Tp = (short*)p;      p += 8192 * 2;
    short* Wp2T  = (short*)p;      p += 65536 * 2;
    short* Wp3T  = (short*)p;      p += 16384 * 2;
    short* Wr1T  = (short*)p;      p += 16384 * 2;
    short* Wr2T  = (short*)p;      p += 65536 * 2;
    float* bp1f  = (float*)p;      p += 256 * 4;
    float* bp2f  = (float*)p;      p += 256 * 4;
    float* bp3f  = (float*)p;      p += 64 * 4;
    float* br1f  = (float*)p;      p += 256 * 4;
    float* br2f  = (float*)p;      p += 256 * 4;
    float* Wr3f  = (float*)p;      p += 512 * 4;
    float* br3f  = (float*)p;      p += 256;
    const size_t required = (size_t)(p - (char*)d_ws);
    if (ws_size < required) return;  // signature: output stays zero (absmax ~26)

    rowptr_kernel<<<(NA + 256) / 256, 256, 0, stream>>>(ids, rp);
    prep_weights_kernel<<<64, 256, 0, stream>>>(
        d_in[2], d_in[3], d_in[4], d_in[5], d_in[6], d_in[7],
        d_in[8], d_in[9], d_in[10], d_in[11], d_in[12], d_in[13],
        Wp1Tp, Wp2T, Wp3T, Wr1T, Wr2T,
        bp1f, bp2f, bp3f, br1f, br2f, Wr3f, br3f, flag);
    fused_kernel<<<NA / AGB, 256, 0, stream>>>(
        ef, ids, rp, Wp1Tp, bp1f, Wp2T, bp2f, Wp3T, bp3f,
        Wr1T, br1f, Wr2T, br2f, Wr3f, br3f, d_out, flag);
}

// Round 10
// 516.408 us; speedup vs baseline: 1.5881x; 1.5881x over previous
//
#include <hip/hip_runtime.h>
#include <hip/hip_bf16.h>

typedef __hip_bfloat16 bf16;
typedef __attribute__((ext_vector_type(8))) short short8;   // MFMA A/B frag (8 bf16)
typedef __attribute__((ext_vector_type(4))) float floatx4;  // MFMA C/D frag

#define NE 524288
#define NA 16384
#define E   64       // edges per chunk
#define AGB 16       // agents per block
#define S1 260       // LDS act row stride (shorts)
#define SH3 68       // h3 overlay row stride (floats), inside wave's own quarter
#define SACC 68      // acc row stride (floats): 64 feats + 2 cb + 2 pad

__device__ __forceinline__ float ld(const void* p, long i, int f32) {
    return f32 ? ((const float*)p)[i] : __bfloat162float(((const bf16*)p)[i]);
}
__device__ __forceinline__ short f2bs(float f) {
    bf16 h = __float2bfloat16(f);
    return *(short*)&h;
}
__device__ __forceinline__ float bs2f(short s) {
    union { unsigned u; float f; } c;
    c.u = ((unsigned)(unsigned short)s) << 16;
    return c.f;
}
__device__ __forceinline__ unsigned pk(float a, float b) {
    return ((unsigned)(unsigned short)f2bs(b) << 16) | (unsigned)(unsigned short)f2bs(a);
}

// ---------------------------------------------------------------------------
// rowptr: rp[a] = lower_bound(ids, a); rp[NA] = NE. ids is sorted.
// ---------------------------------------------------------------------------
__global__ void rowptr_kernel(const int* __restrict__ ids, int* __restrict__ rp) {
    const int i = blockIdx.x * blockDim.x + threadIdx.x;
    if (i > NA) return;
    if (i == NA) { rp[i] = NE; return; }
    int lo = 0, hi = NE;
    while (lo < hi) {
        const int mid = (lo + hi) >> 1;
        if (ids[mid] < i) lo = mid + 1; else hi = mid;
    }
    rp[i] = lo;
}

// ---------------------------------------------------------------------------
// Weight prep (dtype detector fused in). Coalesced transpose reads.
// ---------------------------------------------------------------------------
__global__ void prep_weights_kernel(
    const void* __restrict__ Wp1, const void* __restrict__ bp1,
    const void* __restrict__ Wp2, const void* __restrict__ bp2,
    const void* __restrict__ Wp3, const void* __restrict__ bp3,
    const void* __restrict__ Wr1, const void* __restrict__ br1,
    const void* __restrict__ Wr2, const void* __restrict__ br2,
    const void* __restrict__ Wr3, const void* __restrict__ br3,
    short* __restrict__ Wp1Tp, short* __restrict__ Wp2T, short* __restrict__ Wp3T,
    short* __restrict__ Wr1T,  short* __restrict__ Wr2T,
    float* __restrict__ bp1f, float* __restrict__ bp2f, float* __restrict__ bp3f,
    float* __restrict__ br1f, float* __restrict__ br2f,
    float* __restrict__ Wr3f, float* __restrict__ br3f,
    int* __restrict__ flag)
{
    __shared__ int sflag;
    if (threadIdx.x < 64) {
        const unsigned short* w = (const unsigned short*)Wp2;
        int bad = 0;
        for (int i = threadIdx.x; i < 1024; i += 64) {
            const int e = (w[i] >> 7) & 0xFF;
            if (e >= 131) bad = 1;                // |v|>=16 / inf / nan -> f32 bits
        }
        const unsigned long long m = __ballot(bad);
        if (threadIdx.x == 0) {
            sflag = (m != 0ull) ? 1 : 0;
            if (blockIdx.x == 0) *flag = sflag;
        }
    }
    __syncthreads();
    const int f32 = sflag;

    const int stride = gridDim.x * blockDim.x;
    for (int i = blockIdx.x * blockDim.x + threadIdx.x; i < 173634; i += stride) {
        if (i < 65536) {                       // Wp2: i = k*256+n (coalesced read)
            const int k = i >> 8, n = i & 255;
            Wp2T[n * 256 + k] = f2bs(ld(Wp2, i, f32));
        } else if (i < 81920) {                // Wp3: j = k*64+n (coalesced read)
            const int j = i - 65536, k = j >> 6, n = j & 63;
            Wp3T[n * 256 + k] = f2bs(ld(Wp3, j, f32));
        } else if (i < 90112) {                // Wp1Tp[n][k<32], zero-pad k>=4
            const int j = i - 81920, n = j >> 5, k = j & 31;
            Wp1Tp[j] = (k < 4) ? f2bs(ld(Wp1, (long)k * 256 + n, f32)) : (short)0;
        } else if (i < 106496) {               // Wr1: j = k*256+n (coalesced read)
            const int j = i - 90112, k = j >> 8, n = j & 255;
            Wr1T[n * 64 + k] = f2bs(ld(Wr1, j, f32));
        } else if (i < 172032) {               // Wr2: j = k*256+n (coalesced read)
            const int j = i - 106496, k = j >> 8, n = j & 255;
            Wr2T[n * 256 + k] = f2bs(ld(Wr2, j, f32));
        } else if (i < 172288) { bp1f[i - 172032] = ld(bp1, i - 172032, f32); }
        else if (i < 172544) { bp2f[i - 172288] = ld(bp2, i - 172288, f32); }
        else if (i < 172608) { bp3f[i - 172544] = ld(bp3, i - 172544, f32); }
        else if (i < 172864) { br1f[i - 172608] = ld(br1, i - 172608, f32); }
        else if (i < 173120) { br2f[i - 172864] = ld(br2, i - 172864, f32); }
        else if (i < 173632) { Wr3f[i - 173120] = ld(Wr3, i - 173120, f32); }
        else                 { br3f[i - 173632] = ld(br3, i - 173632, f32); }
    }
}

// ---------------------------------------------------------------------------
// FUSED kernel: block b owns agents [b*16, b*16+16) and their contiguous
// edge range [rp[a0], rp[a0+16]) (ids sorted). Edge MLP chunks of 64 edges
// accumulate h3 + barrier into a 17x68 f32 LDS accumulator, then the agent
// MLP runs in-block. No global atomics, no agg round-trip, single launch.
// R10: __launch_bounds__(256, 2) — 256-reg budget so LICM's loop-invariant
// hoists (Wp1 frags, biases, addresses) FIT instead of spilling to scratch
// (R9's 404 MB scratch writes evicted the L2 weight set -> 1.45 GB HBM).
// ---------------------------------------------------------------------------
__global__ __launch_bounds__(256, 2) void fused_kernel(
    const void* __restrict__ ef, const int* __restrict__ ids,
    const int* __restrict__ rp,
    const short* __restrict__ Wp1Tp, const float* __restrict__ bp1f,
    const short* __restrict__ Wp2T, const float* __restrict__ bp2f,
    const short* __restrict__ Wp3T, const float* __restrict__ bp3f,
    const short* __restrict__ Wr1T, const float* __restrict__ br1f,
    const short* __restrict__ Wr2T, const float* __restrict__ br2f,
    const float* __restrict__ Wr3f, const float* __restrict__ br3f,
    void* __restrict__ out, const int* __restrict__ flag)
{
    __shared__ __align__(16) short hs[E * S1];        // 33.3 KB act buffer
    __shared__ __align__(16) float accf[17 * SACC];   // 4.6 KB agent accumulator
    __shared__ int sid[E];

    const int t = threadIdx.x;
    const int f32 = *flag;
    const int wave = t >> 6, lane = t & 63, quad = lane >> 4, ln = lane & 15;
    const int nb = wave * 64;
    const int a0 = blockIdx.x * AGB;
    const int rs = rp[a0], re = rp[a0 + AGB];

    for (int i = t; i < 17 * SACC; i += 256) accf[i] = 0.f;

    float* h3f = (float*)&hs[wave * 16 * S1];   // wave's own quarter (h3 overlay)
    const int nch = (re - rs + 63) >> 6;

    for (int c = 0; c < nch; ++c) {
        __syncthreads();   // covers acc-init (c=0) / prev chunk's scatter reads
        const long e0 = (long)rs + (long)c * 64;

        // ---- stage: sid + barrier contribution ----
        if (t < E) {
            const long e = e0 + t;
            int idx = 16;                       // trash row for tail lanes
            if (e < re) {
                idx = ids[e] - a0;
                const float px = ld(ef, e * 4 + 0, f32);
                const float py = ld(ef, e * 4 + 1, f32);
                const float d = sqrtf(px * px + py * py);
                const float inv = 1.0f / (d * (d - 0.18f));
                atomicAdd(&accf[idx * SACC + 64], -px * inv);
                atomicAdd(&accf[idx * SACC + 65], -py * inv);
            }
            sid[t] = idx;
        }

        // ---- layer 1: h1 = relu(x @ Wp1 + bp1); A=Wp1^T, B=x frags ----
        {
            short8 b[4];
            #pragma unroll
            for (int mt = 0; mt < 4; ++mt) {
                short8 v = {};
                const long e = e0 + mt * 16 + ln;
                if (quad == 0 && e < re) {
                    if (f32) {
                        const float4 x = ((const float4*)ef)[e];
                        v[0] = f2bs(x.x); v[1] = f2bs(x.y); v[2] = f2bs(x.z); v[3] = f2bs(x.w);
                    } else {
                        const int2 x = ((const int2*)ef)[e];
                        v[0] = (short)(x.x & 0xffff); v[1] = (short)((unsigned)x.x >> 16);
                        v[2] = (short)(x.y & 0xffff); v[3] = (short)((unsigned)x.y >> 16);
                    }
                }
                b[mt] = v;
            }
            floatx4 acc[4][4];
            #pragma unroll
            for (int nt = 0; nt < 4; ++nt) {
                const float4 bv = *(const float4*)&bp1f[nb + nt * 16 + quad * 4];
                const floatx4 bi = { bv.x, bv.y, bv.z, bv.w };
                #pragma unroll
                for (int mt = 0; mt < 4; ++mt) acc[mt][nt] = bi;
            }
            #pragma unroll
            for (int nt = 0; nt < 4; ++nt) {
                const short8 a = *(const short8*)&Wp1Tp[(nb + nt * 16 + ln) * 32 + quad * 8];
                #pragma unroll
                for (int mt = 0; mt < 4; ++mt)
                    acc[mt][nt] = __builtin_amdgcn_mfma_f32_16x16x32_bf16(a, b[mt], acc[mt][nt], 0, 0, 0);
            }
            #pragma unroll
            for (int mt = 0; mt < 4; ++mt)
                #pragma unroll
                for (int nt = 0; nt < 4; ++nt) {
                    const floatx4 v = acc[mt][nt];
                    uint2 w;
                    w.x = pk(fmaxf(v[0], 0.f), fmaxf(v[1], 0.f));
                    w.y = pk(fmaxf(v[2], 0.f), fmaxf(v[3], 0.f));
                    *(uint2*)&hs[(mt * 16 + ln) * S1 + nb + nt * 16 + quad * 4] = w;
                }
        }
        __syncthreads();

        // ---- layer 2: h2 = relu(h1 @ Wp2 + bp2); lookahead-1 prefetch ----
        short8 v3cur[4];
        {
            floatx4 acc[4][4];
            #pragma unroll
            for (int nt = 0; nt < 4; ++nt) {
                const float4 bv = *(const float4*)&bp2f[nb + nt * 16 + quad * 4];
                const floatx4 bi = { bv.x, bv.y, bv.z, bv.w };
                #pragma unroll
                for (int mt = 0; mt < 4; ++mt) acc[mt][nt] = bi;
            }
            short8 wcur[4], wnxt[4];
            #pragma unroll
            for (int nt = 0; nt < 4; ++nt)
                wcur[nt] = *(const short8*)&Wp2T[(nb + nt * 16 + ln) * 256 + quad * 8];
            #pragma unroll
            for (int ks = 0; ks < 8; ++ks) {
                if (ks < 7) {
                    #pragma unroll
                    for (int nt = 0; nt < 4; ++nt)
                        wnxt[nt] = *(const short8*)&Wp2T[(nb + nt * 16 + ln) * 256 + (ks + 1) * 32 + quad * 8];
                }
                short8 b[4];
                #pragma unroll
                for (int mt = 0; mt < 4; ++mt)
                    b[mt] = *(const short8*)&hs[(mt * 16 + ln) * S1 + ks * 32 + quad * 8];
                #pragma unroll
                for (int mt = 0; mt < 4; ++mt)
                    #pragma unroll
                    for (int nt = 0; nt < 4; ++nt)
                        acc[mt][nt] = __builtin_amdgcn_mfma_f32_16x16x32_bf16(wcur[nt], b[mt], acc[mt][nt], 0, 0, 0);
                #pragma unroll
                for (int nt = 0; nt < 4; ++nt) wcur[nt] = wnxt[nt];
            }
            // L3 ks=0 weights issued here: latency overlaps barrier + epilogue
            #pragma unroll
            for (int nt = 0; nt < 4; ++nt)
                v3cur[nt] = *(const short8*)&Wp3T[(nt * 16 + ln) * 256 + quad * 8];

            __syncthreads();   // all h1 reads complete before overwrite
            #pragma unroll
            for (int mt = 0; mt < 4; ++mt)
                #pragma unroll
                for (int nt = 0; nt < 4; ++nt) {
                    const floatx4 v = acc[mt][nt];
                    uint2 w;
                    w.x = pk(fmaxf(v[0], 0.f), fmaxf(v[1], 0.f));
                    w.y = pk(fmaxf(v[2], 0.f), fmaxf(v[3], 0.f));
                    *(uint2*)&hs[(mt * 16 + ln) * S1 + nb + nt * 16 + quad * 4] = w;
                }
        }
        __syncthreads();

        // ---- layer 3: h3 = h2 @ Wp3 + bp3; per-wave 16-edge tile ----
        {
            floatx4 acc[4];
            #pragma unroll
            for (int nt = 0; nt < 4; ++nt) {
                const float4 bv = *(const float4*)&bp3f[nt * 16 + quad * 4];
                acc[nt] = (floatx4){ bv.x, bv.y, bv.z, bv.w };
            }
            short8 v3nxt[4];
            #pragma unroll
            for (int ks = 0; ks < 8; ++ks) {
                if (ks < 7) {
                    #pragma unroll
                    for (int nt = 0; nt < 4; ++nt)
                        v3nxt[nt] = *(const short8*)&Wp3T[(nt * 16 + ln) * 256 + (ks + 1) * 32 + quad * 8];
                }
                const short8 b = *(const short8*)&hs[(wave * 16 + ln) * S1 + ks * 32 + quad * 8];
                #pragma unroll
                for (int nt = 0; nt < 4; ++nt)
                    acc[nt] = __builtin_amdgcn_mfma_f32_16x16x32_bf16(v3cur[nt], b, acc[nt], 0, 0, 0);
                #pragma unroll
                for (int nt = 0; nt < 4; ++nt) v3cur[nt] = v3nxt[nt];
            }
            #pragma unroll
            for (int nt = 0; nt < 4; ++nt) {
                float4 v = { acc[nt][0], acc[nt][1], acc[nt][2], acc[nt][3] };
                *(float4*)&h3f[ln * SH3 + nt * 16 + quad * 4] = v;
            }
        }

        // ---- scatter: run-length combine into LDS accumulator ----
        {
            const int w0 = wave * 16;
            int cur = sid[w0];
            float local = h3f[lane];
            #pragma unroll
            for (int e = 1; e < 16; ++e) {
                const int id = sid[w0 + e];
                const float v = h3f[e * SH3 + lane];
                if (id == cur) local += v;
                else { atomicAdd(&accf[cur * SACC + lane], local); cur = id; local = v; }
            }
            atomicAdd(&accf[cur * SACC + lane], local);
        }
    }
    __syncthreads();

    // ================= agent MLP on this block's 16 agents =================
    // ---- r1 = relu(accbf @ Wr1 + br1), M=16, K=64 ----
    {
        floatx4 acc[4];
        #pragma unroll
        for (int nt = 0; nt < 4; ++nt) {
            const float4 bv = *(const float4*)&br1f[nb + nt * 16 + quad * 4];
            acc[nt] = (floatx4){ bv.x, bv.y, bv.z, bv.w };
        }
        #pragma unroll
        for (int ks = 0; ks < 2; ++ks) {
            const float4 f0 = *(const float4*)&accf[ln * SACC + ks * 32 + quad * 8];
            const float4 f1 = *(const float4*)&accf[ln * SACC + ks * 32 + quad * 8 + 4];
            short8 b;
            b[0] = f2bs(f0.x); b[1] = f2bs(f0.y); b[2] = f2bs(f0.z); b[3] = f2bs(f0.w);
            b[4] = f2bs(f1.x); b[5] = f2bs(f1.y); b[6] = f2bs(f1.z); b[7] = f2bs(f1.w);
            #pragma unroll
            for (int nt = 0; nt < 4; ++nt) {
                const short8 a = *(const short8*)&Wr1T[(nb + nt * 16 + ln) * 64 + ks * 32 + quad * 8];
                acc[nt] = __builtin_amdgcn_mfma_f32_16x16x32_bf16(a, b, acc[nt], 0, 0, 0);
            }
        }
        __syncthreads();   // hs free (last h3f read done above)
        #pragma unroll
        for (int nt = 0; nt < 4; ++nt) {
            const floatx4 v = acc[nt];
            uint2 w;
            w.x = pk(fmaxf(v[0], 0.f), fmaxf(v[1], 0.f));
            w.y = pk(fmaxf(v[2], 0.f), fmaxf(v[3], 0.f));
            *(uint2*)&hs[ln * S1 + nb + nt * 16 + quad * 4] = w;
        }
    }
    __syncthreads();

    // ---- r2 = relu(r1 @ Wr2 + br2), M=16, K=256 ----
    {
        floatx4 acc[4];
        #pragma unroll
        for (int nt = 0; nt < 4; ++nt) {
            const float4 bv = *(const float4*)&br2f[nb + nt * 16 + quad * 4];
            acc[nt] = (floatx4){ bv.x, bv.y, bv.z, bv.w };
        }
        short8 wcur[4], wnxt[4];
        #pragma unroll
        for (int nt = 0; nt < 4; ++nt)
            wcur[nt] = *(const short8*)&Wr2T[(nb + nt * 16 + ln) * 256 + quad * 8];
        #pragma unroll
        for (int ks = 0; ks < 8; ++ks) {
            if (ks < 7) {
                #pragma unroll
                for (int nt = 0; nt < 4; ++nt)
                    wnxt[nt] = *(const short8*)&Wr2T[(nb + nt * 16 + ln) * 256 + (ks + 1) * 32 + quad * 8];
            }
            const short8 b = *(const short8*)&hs[ln * S1 + ks * 32 + quad * 8];
            #pragma unroll
            for (int nt = 0; nt < 4; ++nt)
                acc[nt] = __builtin_amdgcn_mfma_f32_16x16x32_bf16(wcur[nt], b, acc[nt], 0, 0, 0);
            #pragma unroll
            for (int nt = 0; nt < 4; ++nt) wcur[nt] = wnxt[nt];
        }
        __syncthreads();   // all r1 reads done
        #pragma unroll
        for (int nt = 0; nt < 4; ++nt) {
            const floatx4 v = acc[nt];
            uint2 w;
            w.x = pk(fmaxf(v[0], 0.f), fmaxf(v[1], 0.f));
            w.y = pk(fmaxf(v[2], 0.f), fmaxf(v[3], 0.f));
            *(uint2*)&hs[ln * S1 + nb + nt * 16 + quad * 4] = w;
        }
    }
    __syncthreads();

    // ---- out = r2 @ Wr3 + br3 + barrier (N=2, VALU, 16-way K-split) ----
    float* partf = (float*)&hs[16 * S1];   // rows 16+ are free
    {
        const int m = t & 15;              // agent
        const int p = t >> 4;              // 16 K-parts of 16
        const int k0 = p * 16;
        const short8 h0 = *(const short8*)&hs[m * S1 + k0];
        const short8 h1 = *(const short8*)&hs[m * S1 + k0 + 8];
        float v0 = 0.f, v1 = 0.f;
        #pragma unroll
        for (int j = 0; j < 8; ++j) {
            const float a = bs2f(h0[j]), b = bs2f(h1[j]);
            v0 = fmaf(a, Wr3f[(k0 + j) * 2 + 0], fmaf(b, Wr3f[(k0 + 8 + j) * 2 + 0], v0));
            v1 = fmaf(a, Wr3f[(k0 + j) * 2 + 1], fmaf(b, Wr3f[(k0 + 8 + j) * 2 + 1], v1));
        }
        partf[(p * 16 + m) * 2 + 0] = v0;
        partf[(p * 16 + m) * 2 + 1] = v1;
    }
    __syncthreads();
    if (t < 32) {
        const int m = t >> 1, o = t & 1;
        float s = br3f[o] + accf[m * SACC + 64 + o];
        #pragma unroll
        for (int p = 0; p < 16; ++p) s += partf[(p * 16 + m) * 2 + o];
        if (f32) ((float*)out)[(a0 + m) * 2 + o] = s;
        else     ((bf16*)out)[(a0 + m) * 2 + o] = __float2bfloat16(s);
    }
}

extern "C" void kernel_launch(void* const* d_in, const int* in_sizes, int n_in,
                              void* d_out, int out_size, void* d_ws, size_t ws_size,
                              hipStream_t stream)
{
    (void)in_sizes; (void)n_in; (void)out_size;

    const void* ef  = d_in[0];
    const int*  ids = (const int*)d_in[1];

    char* p = (char*)d_ws;
    int*   flag  = (int*)p;        p += 256;
    int*   rp    = (int*)p;        p += (NA + 1 + 63) / 64 * 64 * 4;
    short* Wp1Tp = (short*)p;      p += 8192 * 2;
    short* Wp2T  = (short*)p;      p += 65536 * 2;
    short* Wp3T  = (short*)p;      p += 16384 * 2;
    short* Wr1T  = (short*)p;      p += 16384 * 2;
    short* Wr2T  = (short*)p;      p += 65536 * 2;
    float* bp1f  = (float*)p;      p += 256 * 4;
    float* bp2f  = (float*)p;      p += 256 * 4;
    float* bp3f  = (float*)p;      p += 64 * 4;
    float* br1f  = (float*)p;      p += 256 * 4;
    float* br2f  = (float*)p;      p += 256 * 4;
    float* Wr3f  = (float*)p;      p += 512 * 4;
    float* br3f  = (float*)p;      p += 256;
    const size_t required = (size_t)(p - (char*)d_ws);
    if (ws_size < required) return;  // signature: output stays zero (absmax ~26)

    rowptr_kernel<<<(NA + 256) / 256, 256, 0, stream>>>(ids, rp);
    prep_weights_kernel<<<64, 256, 0, stream>>>(
        d_in[2], d_in[3], d_in[4], d_in[5], d_in[6], d_in[7],
        d_in[8], d_in[9], d_in[10], d_in[11], d_in[12], d_in[13],
        Wp1Tp, Wp2T, Wp3T, Wr1T, Wr2T,
        bp1f, bp2f, bp3f, br1f, br2f, Wr3f, br3f, flag);
    fused_kernel<<<NA / AGB, 256, 0, stream>>>(
        ef, ids, rp, Wp1Tp, bp1f, Wp2T, bp2f, Wp3T, bp3f,
        Wr1T, br1f, Wr2T, br2f, Wr3f, br3f, d_out, flag);
}